// Round 1
// baseline (1724.636 us; speedup 1.0000x reference)
//
#include <hip/hip_runtime.h>
#include <math.h>

#define TB 256

constexpr int B_ = 4, S_ = 2048, HID_ = 1024, H_ = 16, KV_ = 4, D_ = 64;

// ---- workspace layout (float offsets) ----
constexpr size_t KT_OFF  = 0;                               // Kt[a][b][kv][d][k]
constexpr size_t KT_SZ   = (size_t)2 * B_ * KV_ * D_ * S_;  // 4,194,304
constexpr size_t U_OFF   = KT_OFF + KT_SZ;                  // U[a][b][h][k]
constexpr size_t U_SZ    = (size_t)2 * B_ * H_ * S_;        // 262,144
constexpr size_t WVO_OFF = U_OFF + U_SZ;                    // wvoT[c][n], n=a*16+h
constexpr size_t WVO_SZ  = (size_t)HID_ * 32;               // 32,768
constexpr size_t SH_OFF  = WVO_OFF + WVO_SZ;                // Sh[a*4+b][q][h]
constexpr size_t SH_SZ   = (size_t)2 * B_ * S_ * H_;        // 262,144
constexpr size_t W_OFF   = SH_OFF + SH_SZ;                  // w[b][q]
constexpr size_t W_SZ    = (size_t)B_ * S_;                 // 8,192
constexpr size_t SUM_OFF = W_OFF + W_SZ;                    // 4 doubles (8 floats), 8B-aligned
constexpr size_t SIZES_OFF = SUM_OFF + 8;                   // 4 ints

// ---- fold Wv @ Wo per head: wvoT[c][a*16+h] ----
__global__ __launch_bounds__(TB) void wvo_kernel(
    const float* __restrict__ Wv1, const float* __restrict__ Wo1,
    const float* __restrict__ Wv2, const float* __restrict__ Wo2,
    float* __restrict__ ws) {
  int n = blockIdx.x;  // a*16+h
  int a = n >> 4, h = n & 15, kv = h >> 2;
  const float* Wv = a ? Wv2 : Wv1;
  const float* Wo = a ? Wo2 : Wo1;
  for (int c = threadIdx.x; c < HID_; c += TB) {
    const float* vr = Wv + (size_t)c * (KV_ * D_) + kv * D_;
    const float* wo = Wo + h * D_;
    float acc = 0.f;
#pragma unroll 16
    for (int d = 0; d < D_; ++d) acc += vr[d] * wo[d];
    ws[WVO_OFF + (size_t)c * 32 + n] = acc;
  }
}

// ---- K projection, stored transposed: Kt[a][b][kv][d][k] ----
__global__ __launch_bounds__(TB) void k_gemm_kernel(
    const float* __restrict__ x, const float* __restrict__ Wk1,
    const float* __restrict__ Wk2, float* __restrict__ ws) {
  __shared__ float xs[64][68];   // [k][c]
  __shared__ float wk[64][68];   // [c][d]
  int k0 = blockIdx.x * 64;
  int kv = blockIdx.y;
  int ab = blockIdx.z, a = ab >> 2, b = ab & 3;
  const float* Wk = a ? Wk2 : Wk1;
  int tid = threadIdx.x;
  int tk = tid & 15, td = tid >> 4;
  int lr = tid >> 4, lc4 = (tid & 15) * 4;
  float acc[4][4] = {};
  for (int c0 = 0; c0 < HID_; c0 += 64) {
    __syncthreads();
#pragma unroll
    for (int p = 0; p < 4; ++p) {
      int r = lr + p * 16;
      *reinterpret_cast<float4*>(&xs[r][lc4]) =
          *reinterpret_cast<const float4*>(x + ((size_t)(b * S_ + k0 + r) * HID_ + c0 + lc4));
      *reinterpret_cast<float4*>(&wk[r][lc4]) =
          *reinterpret_cast<const float4*>(Wk + ((size_t)(c0 + r) * (KV_ * D_) + kv * D_ + lc4));
    }
    __syncthreads();
#pragma unroll 8
    for (int cc = 0; cc < 64; ++cc) {
      float4 wv = *reinterpret_cast<const float4*>(&wk[cc][td * 4]);
      float xv[4];
#pragma unroll
      for (int i = 0; i < 4; ++i) xv[i] = xs[tk * 4 + i][cc];
#pragma unroll
      for (int i = 0; i < 4; ++i) {
        acc[i][0] += xv[i] * wv.x; acc[i][1] += xv[i] * wv.y;
        acc[i][2] += xv[i] * wv.z; acc[i][3] += xv[i] * wv.w;
      }
    }
  }
  float* Kt = ws + KT_OFF + ((size_t)(a * B_ + b) * KV_ + kv) * D_ * S_;
#pragma unroll
  for (int j = 0; j < 4; ++j) {
    float4 v = make_float4(acc[0][j], acc[1][j], acc[2][j], acc[3][j]);
    *reinterpret_cast<float4*>(Kt + (size_t)(td * 4 + j) * S_ + k0 + tk * 4) = v;
  }
}

// ---- U = x @ wvoT : U[a][b][h][k] ----
__global__ __launch_bounds__(TB) void u_gemm_kernel(
    const float* __restrict__ x, float* __restrict__ ws) {
  __shared__ float xs[64][68];   // [k][c]
  __shared__ float uw[64][36];   // [c][n]
  int k0 = blockIdx.x * 64, b = blockIdx.y;
  int tid = threadIdx.x;
  int tk = tid >> 2, ng = tid & 3;
  int lr = tid >> 4, lc4 = (tid & 15) * 4;
  float acc[8] = {};
  for (int c0 = 0; c0 < HID_; c0 += 64) {
    __syncthreads();
#pragma unroll
    for (int p = 0; p < 4; ++p) {
      int r = lr + p * 16;
      *reinterpret_cast<float4*>(&xs[r][lc4]) =
          *reinterpret_cast<const float4*>(x + ((size_t)(b * S_ + k0 + r) * HID_ + c0 + lc4));
    }
    {
      int cc = tid >> 3, n4 = (tid & 7) * 4;
      *reinterpret_cast<float4*>(&uw[cc][n4]) =
          *reinterpret_cast<const float4*>(ws + WVO_OFF + (size_t)(c0 + cc) * 32 + n4);
      *reinterpret_cast<float4*>(&uw[cc + 32][n4]) =
          *reinterpret_cast<const float4*>(ws + WVO_OFF + (size_t)(c0 + cc + 32) * 32 + n4);
    }
    __syncthreads();
#pragma unroll 8
    for (int cc = 0; cc < 64; ++cc) {
      float xv = xs[tk][cc];
      float4 a0 = *reinterpret_cast<const float4*>(&uw[cc][ng * 8]);
      float4 a1 = *reinterpret_cast<const float4*>(&uw[cc][ng * 8 + 4]);
      acc[0] += xv * a0.x; acc[1] += xv * a0.y; acc[2] += xv * a0.z; acc[3] += xv * a0.w;
      acc[4] += xv * a1.x; acc[5] += xv * a1.y; acc[6] += xv * a1.z; acc[7] += xv * a1.w;
    }
  }
#pragma unroll
  for (int j = 0; j < 8; ++j) {
    int n = ng * 8 + j, a = n >> 4, h = n & 15;
    ws[U_OFF + ((size_t)(a * B_ + b) * H_ + h) * S_ + k0 + tk] = acc[j];
  }
}

// ---- fused: Q-proj (per head) + QK^T + softmax-with-scalar-value ----
// grid: (qtile=32, ah=32, b=4); per-head partial s written to Sh.
__global__ __launch_bounds__(TB) void attn_kernel(
    const float* __restrict__ x, const float* __restrict__ Wq1,
    const float* __restrict__ Wq2, float* __restrict__ ws) {
  __shared__ float Qt[64][68];    // [d][q]
  __shared__ float bufA[64][68];  // phase A: xs[q][c]; phase B: Kt[d][k]
  __shared__ float bufB[64][68];  // phase A: wq[c][d]; phase B: u[k] in row 0
  int q0 = blockIdx.x * 64;
  int ah = blockIdx.y, a = ah >> 4, h = ah & 15, kv = h >> 2;
  int b = blockIdx.z;
  const float* Wq = a ? Wq2 : Wq1;
  int tid = threadIdx.x;
  int tq = tid >> 4, td = tid & 15;
  int lr = tid >> 4, lc4 = (tid & 15) * 4;

  // Phase A: Qt[d][q] = (x @ Wq[:, h*64+d]) for this q-tile
  {
    float acc[4][4] = {};
    for (int c0 = 0; c0 < HID_; c0 += 64) {
      __syncthreads();
#pragma unroll
      for (int p = 0; p < 4; ++p) {
        int r = lr + p * 16;
        *reinterpret_cast<float4*>(&bufA[r][lc4]) =
            *reinterpret_cast<const float4*>(x + ((size_t)(b * S_ + q0 + r) * HID_ + c0 + lc4));
        *reinterpret_cast<float4*>(&bufB[r][lc4]) =
            *reinterpret_cast<const float4*>(Wq + ((size_t)(c0 + r) * (H_ * D_) + h * D_ + lc4));
      }
      __syncthreads();
#pragma unroll 8
      for (int cc = 0; cc < 64; ++cc) {
        float4 wv = *reinterpret_cast<const float4*>(&bufB[cc][td * 4]);
        float xv[4];
#pragma unroll
        for (int i = 0; i < 4; ++i) xv[i] = bufA[tq * 4 + i][cc];
#pragma unroll
        for (int i = 0; i < 4; ++i) {
          acc[i][0] += xv[i] * wv.x; acc[i][1] += xv[i] * wv.y;
          acc[i][2] += xv[i] * wv.z; acc[i][3] += xv[i] * wv.w;
        }
      }
    }
    __syncthreads();
#pragma unroll
    for (int i = 0; i < 4; ++i)
#pragma unroll
      for (int j = 0; j < 4; ++j)
        Qt[td * 4 + j][tq * 4 + i] = acc[i][j];
  }

  // Phase B: stream K tiles; scores -> exp -> accumulate num/den (value dim = 1)
  const float* Ktg = ws + KT_OFF + ((size_t)(a * B_ + b) * KV_ + kv) * D_ * S_;
  const float* Ug  = ws + U_OFF + ((size_t)(a * B_ + b) * H_ + h) * S_;
  float num[4] = {}, den[4] = {};
  for (int k0 = 0; k0 < S_; k0 += 64) {
    __syncthreads();
#pragma unroll
    for (int p = 0; p < 4; ++p) {
      int r = lr + p * 16;
      *reinterpret_cast<float4*>(&bufA[r][lc4]) =
          *reinterpret_cast<const float4*>(Ktg + (size_t)r * S_ + k0 + lc4);
    }
    if (tid < 16)
      *reinterpret_cast<float4*>(&bufB[0][tid * 4]) =
          *reinterpret_cast<const float4*>(Ug + k0 + tid * 4);
    __syncthreads();
    float sacc[4][4] = {};
#pragma unroll 8
    for (int cc = 0; cc < 64; ++cc) {
      float4 qv = *reinterpret_cast<const float4*>(&Qt[cc][tq * 4]);
      float4 kt = *reinterpret_cast<const float4*>(&bufA[cc][td * 4]);
      float qa[4] = {qv.x, qv.y, qv.z, qv.w};
      float ka[4] = {kt.x, kt.y, kt.z, kt.w};
#pragma unroll
      for (int i = 0; i < 4; ++i)
#pragma unroll
        for (int j = 0; j < 4; ++j) sacc[i][j] += qa[i] * ka[j];
    }
    float4 uv = *reinterpret_cast<const float4*>(&bufB[0][td * 4]);
    float ua[4] = {uv.x, uv.y, uv.z, uv.w};
#pragma unroll
    for (int i = 0; i < 4; ++i)
#pragma unroll
      for (int j = 0; j < 4; ++j) {
        float e = __expf(sacc[i][j] * 0.125f);
        den[i] += e;
        num[i] += e * ua[j];
      }
  }
  // reduce across the 16 threads (td) sharing each q row
#pragma unroll
  for (int off = 1; off < 16; off <<= 1) {
#pragma unroll
    for (int i = 0; i < 4; ++i) {
      den[i] += __shfl_xor(den[i], off);
      num[i] += __shfl_xor(num[i], off);
    }
  }
  if (td == 0) {
#pragma unroll
    for (int i = 0; i < 4; ++i) {
      int q = q0 + tq * 4 + i;
      ws[SH_OFF + ((size_t)(a * B_ + b) * S_ + q) * H_ + h] = num[i] / den[i];
    }
  }
}

// ---- sum heads; w = sigmoid(s2); fp64 reduce sigmoid(s1) per batch ----
__global__ __launch_bounds__(TB) void post_kernel(float* __restrict__ ws) {
  int g = blockIdx.x * TB + threadIdx.x;
  int b = g >> 11, q = g & (S_ - 1);
  const float* sh = ws + SH_OFF;
  float s1 = 0.f, s2 = 0.f;
#pragma unroll
  for (int h = 0; h < H_; ++h) {
    s1 += sh[((size_t)b * S_ + q) * H_ + h];
    s2 += sh[((size_t)(B_ + b) * S_ + q) * H_ + h];
  }
  ws[W_OFF + g] = 1.f / (1.f + expf(-s2));
  double sig = 1.0 / (1.0 + exp(-(double)s1));
#pragma unroll
  for (int off = 1; off < 64; off <<= 1) sig += __shfl_xor(sig, off);
  __shared__ double red[4];
  int tid = threadIdx.x;
  if ((tid & 63) == 0) red[tid >> 6] = sig;
  __syncthreads();
  if (tid == 0)
    atomicAdd(reinterpret_cast<double*>(ws + SUM_OFF) + b,
              red[0] + red[1] + red[2] + red[3]);
}

__global__ void sizes_kernel(const float* __restrict__ scale_p, float* __restrict__ ws,
                             float* __restrict__ out_sizes) {
  int b = threadIdx.x;
  if (b < B_) {
    double m = reinterpret_cast<const double*>(ws + SUM_OFF)[b] / (double)S_;
    double v = m * (double)(*scale_p) * (double)(8192 - 32) + 32.0;
    int sz = (int)v;  // truncation, matches .astype(int32)
    reinterpret_cast<int*>(ws + SIZES_OFF)[b] = sz;
    out_sizes[b] = (float)sz;
  }
}

// ---- weighted segment pooling with exact np.linspace boundaries ----
__global__ __launch_bounds__(TB) void pool_kernel(
    const float* __restrict__ x, const float* __restrict__ ws,
    float* __restrict__ out, int max_len) {
  int p = blockIdx.x, b = blockIdx.y;
  int sz = reinterpret_cast<const int*>(ws + SIZES_OFF)[b];
  int s = p - (max_len - sz);
  int tid = threadIdx.x;
  size_t obase = ((size_t)b * max_len + p) * HID_;
  size_t maskbase = (size_t)B_ * max_len * HID_;
  if (s < 0) {
    *reinterpret_cast<float4*>(out + obase + tid * 4) = make_float4(0.f, 0.f, 0.f, 0.f);
    if (tid == 0) out[maskbase + (size_t)b * max_len + p] = 0.f;
    return;
  }
  double step = (double)S_ / (double)sz;  // np.linspace step in fp64
  int t0 = (int)floor((double)s * step);
  int t1 = (s + 1 == sz) ? S_ : (int)floor((double)(s + 1) * step);
  const float* wv = ws + W_OFF + (size_t)b * S_;
  const float* xb = x + (size_t)b * S_ * HID_;
  float den = 0.f, acc0 = 0.f, acc1 = 0.f, acc2 = 0.f, acc3 = 0.f;
  for (int t = t0; t < t1; ++t) {
    float wt = wv[t];
    den += wt;
    float4 xv = *reinterpret_cast<const float4*>(xb + (size_t)t * HID_ + tid * 4);
    acc0 += xv.x * wt; acc1 += xv.y * wt; acc2 += xv.z * wt; acc3 += xv.w * wt;
  }
  float d = den + 1e-8f;
  *reinterpret_cast<float4*>(out + obase + tid * 4) =
      make_float4(acc0 / d, acc1 / d, acc2 / d, acc3 / d);
  if (tid == 0) out[maskbase + (size_t)b * max_len + p] = 1.f;
}

extern "C" void kernel_launch(void* const* d_in, const int* in_sizes, int n_in,
                              void* d_out, int out_size, void* d_ws, size_t ws_size,
                              hipStream_t stream) {
  const float* x    = (const float*)d_in[0];
  const float* Wq1  = (const float*)d_in[1];
  const float* Wk1  = (const float*)d_in[2];
  const float* Wv1  = (const float*)d_in[3];
  const float* Wo1  = (const float*)d_in[4];
  const float* Wq2  = (const float*)d_in[5];
  const float* Wk2  = (const float*)d_in[6];
  const float* Wv2  = (const float*)d_in[7];
  const float* Wo2  = (const float*)d_in[8];
  const float* scale = (const float*)d_in[9];
  float* ws  = (float*)d_ws;
  float* out = (float*)d_out;

  // out layout: pooled[B][max_len][HID], mask[B][max_len], sizes[B]
  int max_len = (out_size - B_) / (B_ * (HID_ + 1));

  hipMemsetAsync((void*)(ws + SUM_OFF), 0, 4 * sizeof(double), stream);
  wvo_kernel<<<32, TB, 0, stream>>>(Wv1, Wo1, Wv2, Wo2, ws);
  k_gemm_kernel<<<dim3(S_ / 64, KV_, 8), TB, 0, stream>>>(x, Wk1, Wk2, ws);
  u_gemm_kernel<<<dim3(S_ / 64, B_), TB, 0, stream>>>(x, ws);
  attn_kernel<<<dim3(S_ / 64, 32, B_), TB, 0, stream>>>(x, Wq1, Wq2, ws);
  post_kernel<<<(B_ * S_) / TB, TB, 0, stream>>>(ws);
  float* out_sizes = out + (size_t)B_ * max_len * HID_ + (size_t)B_ * max_len;
  sizes_kernel<<<1, 64, 0, stream>>>(scale, ws, out_sizes);
  pool_kernel<<<dim3(max_len, B_), TB, 0, stream>>>(x, ws, out, max_len);
}

// Round 2
// 1079.149 us; speedup vs baseline: 1.5981x; 1.5981x over previous
//
#include <hip/hip_runtime.h>
#include <math.h>

#define TB 256

constexpr int B_ = 4, S_ = 2048, HID_ = 1024, H_ = 16, KV_ = 4, D_ = 64;

typedef short sh8 __attribute__((ext_vector_type(8)));   // 8 bf16 in 4 VGPRs
typedef float fl4 __attribute__((ext_vector_type(4)));
typedef unsigned short u16;
typedef unsigned int u32;

__device__ __forceinline__ u16 f2bf(float f) {  // RNE float->bf16 bits
  u32 u = __float_as_uint(f);
  u += 0x7fff + ((u >> 16) & 1);
  return (u16)(u >> 16);
}
__device__ __forceinline__ float bf2f(u16 h) { return __uint_as_float(((u32)h) << 16); }

// ---- workspace layout ----
// KH/KL: bf16 hi/lo planes of K, stored in MFMA B-fragment order:
//   per (a,b,kv) plane of 2048k x 64d: frag(k16, ds) = 64 lanes x 8 bf16,
//   elem offset = ((k16*2+ds)*64 + lane)*8 + j, lane = quad*16+col holds
//   K[key = k16*16+col][d = ds*32+quad*8+j].
constexpr size_t KH_SZU  = (size_t)2 * B_ * KV_ * S_ * D_;  // 4,194,304 ushorts
constexpr size_t KPLANE  = (size_t)S_ * D_;                 // 131,072 ushorts per (a,b,kv)
constexpr size_t U_OFF   = 4194304;                         // floats (== KH+KL bytes / 4)
constexpr size_t U_SZ    = (size_t)2 * B_ * H_ * S_;        // 262,144
constexpr size_t WVO_OFF = U_OFF + U_SZ;                    // wvoT[c][n], n=a*16+h
constexpr size_t WVO_SZ  = (size_t)HID_ * 32;               // 32,768
constexpr size_t SH_OFF  = WVO_OFF + WVO_SZ;                // Sh[a*4+b][q][h]
constexpr size_t SH_SZ   = (size_t)2 * B_ * S_ * H_;        // 262,144
constexpr size_t W_OFF   = SH_OFF + SH_SZ;                  // w[b][q]
constexpr size_t W_SZ    = (size_t)B_ * S_;                 // 8,192
constexpr size_t SUM_OFF = W_OFF + W_SZ;                    // 4 doubles
constexpr size_t SIZES_OFF = SUM_OFF + 8;                   // 4 ints

// ---- fold Wv @ Wo per head: wvoT[c][a*16+h] ----
__global__ __launch_bounds__(TB) void wvo_kernel(
    const float* __restrict__ Wv1, const float* __restrict__ Wo1,
    const float* __restrict__ Wv2, const float* __restrict__ Wo2,
    float* __restrict__ ws) {
  int n = blockIdx.x;  // a*16+h
  int a = n >> 4, h = n & 15, kv = h >> 2;
  const float* Wv = a ? Wv2 : Wv1;
  const float* Wo = a ? Wo2 : Wo1;
  for (int c = threadIdx.x; c < HID_; c += TB) {
    const float* vr = Wv + (size_t)c * (KV_ * D_) + kv * D_;
    const float* wo = Wo + h * D_;
    float acc = 0.f;
#pragma unroll 16
    for (int d = 0; d < D_; ++d) acc += vr[d] * wo[d];
    ws[WVO_OFF + (size_t)c * 32 + n] = acc;
  }
}

// ---- K projection -> hi/lo bf16 planes in B-fragment order ----
__global__ __launch_bounds__(TB) void k_gemm_kernel(
    const float* __restrict__ x, const float* __restrict__ Wk1,
    const float* __restrict__ Wk2, float* __restrict__ ws) {
  __shared__ __align__(16) float xs[64][68];   // [k][c]; reused as [key][d] tile
  __shared__ __align__(16) float wk[64][68];   // [c][d]
  int k0 = blockIdx.x * 64;
  int kv = blockIdx.y;
  int ab = blockIdx.z, a = ab >> 2, b = ab & 3;
  const float* Wk = a ? Wk2 : Wk1;
  int tid = threadIdx.x;
  int tk = tid & 15, td = tid >> 4;
  int lr = tid >> 4, lc4 = (tid & 15) * 4;
  float acc[4][4] = {};
  for (int c0 = 0; c0 < HID_; c0 += 64) {
    __syncthreads();
#pragma unroll
    for (int p = 0; p < 4; ++p) {
      int r = lr + p * 16;
      *reinterpret_cast<float4*>(&xs[r][lc4]) =
          *reinterpret_cast<const float4*>(x + ((size_t)(b * S_ + k0 + r) * HID_ + c0 + lc4));
      *reinterpret_cast<float4*>(&wk[r][lc4]) =
          *reinterpret_cast<const float4*>(Wk + ((size_t)(c0 + r) * (KV_ * D_) + kv * D_ + lc4));
    }
    __syncthreads();
#pragma unroll 8
    for (int cc = 0; cc < 64; ++cc) {
      float4 wv = *reinterpret_cast<const float4*>(&wk[cc][td * 4]);
      float xv[4];
#pragma unroll
      for (int i = 0; i < 4; ++i) xv[i] = xs[tk * 4 + i][cc];
#pragma unroll
      for (int i = 0; i < 4; ++i) {
        acc[i][0] += xv[i] * wv.x; acc[i][1] += xv[i] * wv.y;
        acc[i][2] += xv[i] * wv.z; acc[i][3] += xv[i] * wv.w;
      }
    }
  }
  // stage tile to LDS as [key][d], then emit hi/lo bf16 fragments
  __syncthreads();
#pragma unroll
  for (int i = 0; i < 4; ++i)
    *reinterpret_cast<float4*>(&xs[tk * 4 + i][td * 4]) =
        make_float4(acc[i][0], acc[i][1], acc[i][2], acc[i][3]);
  __syncthreads();
  u16* KH = (u16*)ws;
  u16* KL = KH + KH_SZU;
  size_t plane = (size_t)((a * B_ + b) * KV_ + kv) * KPLANE;
  int lane = tid & 63, quad = lane >> 4, col = lane & 15;
#pragma unroll
  for (int t = 0; t < 2; ++t) {
    int f = (tid >> 6) + t * 4;          // 0..7
    int k16 = f & 3, ds = f >> 2;
    const float* row = &xs[k16 * 16 + col][ds * 32 + quad * 8];
    sh8 hh, ll;
#pragma unroll
    for (int j = 0; j < 8; ++j) {
      float v = row[j];
      u16 hb = f2bf(v);
      hh[j] = (short)hb;
      ll[j] = (short)f2bf(v - bf2f(hb));
    }
    size_t fb = plane + ((size_t)(((k0 >> 4) + k16) * 2 + ds)) * 512 + (size_t)lane * 8;
    *reinterpret_cast<sh8*>(KH + fb) = hh;
    *reinterpret_cast<sh8*>(KL + fb) = ll;
  }
}

// ---- U = x @ wvoT : U[a][b][h][k] ----
__global__ __launch_bounds__(TB) void u_gemm_kernel(
    const float* __restrict__ x, float* __restrict__ ws) {
  __shared__ float xs[64][68];   // [k][c]
  __shared__ float uw[64][36];   // [c][n]
  int k0 = blockIdx.x * 64, b = blockIdx.y;
  int tid = threadIdx.x;
  int tk = tid >> 2, ng = tid & 3;
  int lr = tid >> 4, lc4 = (tid & 15) * 4;
  float acc[8] = {};
  for (int c0 = 0; c0 < HID_; c0 += 64) {
    __syncthreads();
#pragma unroll
    for (int p = 0; p < 4; ++p) {
      int r = lr + p * 16;
      *reinterpret_cast<float4*>(&xs[r][lc4]) =
          *reinterpret_cast<const float4*>(x + ((size_t)(b * S_ + k0 + r) * HID_ + c0 + lc4));
    }
    {
      int cc = tid >> 3, n4 = (tid & 7) * 4;
      *reinterpret_cast<float4*>(&uw[cc][n4]) =
          *reinterpret_cast<const float4*>(ws + WVO_OFF + (size_t)(c0 + cc) * 32 + n4);
      *reinterpret_cast<float4*>(&uw[cc + 32][n4]) =
          *reinterpret_cast<const float4*>(ws + WVO_OFF + (size_t)(c0 + cc + 32) * 32 + n4);
    }
    __syncthreads();
#pragma unroll 8
    for (int cc = 0; cc < 64; ++cc) {
      float xv = xs[tk][cc];
      float4 a0 = *reinterpret_cast<const float4*>(&uw[cc][ng * 8]);
      float4 a1 = *reinterpret_cast<const float4*>(&uw[cc][ng * 8 + 4]);
      acc[0] += xv * a0.x; acc[1] += xv * a0.y; acc[2] += xv * a0.z; acc[3] += xv * a0.w;
      acc[4] += xv * a1.x; acc[5] += xv * a1.y; acc[6] += xv * a1.z; acc[7] += xv * a1.w;
    }
  }
#pragma unroll
  for (int j = 0; j < 8; ++j) {
    int n = ng * 8 + j, a = n >> 4, h = n & 15;
    ws[U_OFF + ((size_t)(a * B_ + b) * H_ + h) * S_ + k0 + tk] = acc[j];
  }
}

// ---- fused: fp32 Q-proj (phase A) + hi/lo bf16 MFMA QK^T + scalar-value softmax ----
__global__ __launch_bounds__(TB) void attn_kernel(
    const float* __restrict__ x, const float* __restrict__ Wq1,
    const float* __restrict__ Wq2, float* __restrict__ ws) {
  __shared__ __align__(16) float Qt[64][68];    // [d][q] fp32
  __shared__ __align__(16) float bufA[64][68];  // A: xs; B: kbuf (16 KB frag buffer)
  __shared__ __align__(16) float bufB[64][68];  // A: wq; B: u row (64 floats)
  int q0 = blockIdx.x * 64;
  int ah = blockIdx.y, a = ah >> 4, h = ah & 15, kv = h >> 2;
  int b = blockIdx.z;
  const float* Wq = a ? Wq2 : Wq1;
  int tid = threadIdx.x;
  int tq = tid >> 4, td = tid & 15;
  int lr = tid >> 4, lc4 = (tid & 15) * 4;

  // Phase A: Qt[d][q] = (x @ Wq[:, h*64+d]) for this q-tile (fp32 vector)
  {
    float acc[4][4] = {};
    for (int c0 = 0; c0 < HID_; c0 += 64) {
      __syncthreads();
#pragma unroll
      for (int p = 0; p < 4; ++p) {
        int r = lr + p * 16;
        *reinterpret_cast<float4*>(&bufA[r][lc4]) =
            *reinterpret_cast<const float4*>(x + ((size_t)(b * S_ + q0 + r) * HID_ + c0 + lc4));
        *reinterpret_cast<float4*>(&bufB[r][lc4]) =
            *reinterpret_cast<const float4*>(Wq + ((size_t)(c0 + r) * (H_ * D_) + h * D_ + lc4));
      }
      __syncthreads();
#pragma unroll 8
      for (int cc = 0; cc < 64; ++cc) {
        float4 wv = *reinterpret_cast<const float4*>(&bufB[cc][td * 4]);
        float xv[4];
#pragma unroll
        for (int i = 0; i < 4; ++i) xv[i] = bufA[tq * 4 + i][cc];
#pragma unroll
        for (int i = 0; i < 4; ++i) {
          acc[i][0] += xv[i] * wv.x; acc[i][1] += xv[i] * wv.y;
          acc[i][2] += xv[i] * wv.z; acc[i][3] += xv[i] * wv.w;
        }
      }
    }
    __syncthreads();
#pragma unroll
    for (int i = 0; i < 4; ++i)
#pragma unroll
      for (int j = 0; j < 4; ++j)
        Qt[td * 4 + j][tq * 4 + i] = acc[i][j];
  }
  __syncthreads();  // Qt complete before fragment build

  // Build hi/lo Q A-fragments in registers (lane holds Q[q=w*16+col][d=ds*32+quad*8+j])
  int lane = tid & 63, w = tid >> 6, quad = lane >> 4, col = lane & 15;
  sh8 qh[2], ql[2];
#pragma unroll
  for (int ds = 0; ds < 2; ++ds)
#pragma unroll
    for (int j = 0; j < 8; ++j) {
      float v = Qt[ds * 32 + quad * 8 + j][w * 16 + col];
      u16 hb = f2bf(v);
      qh[ds][j] = (short)hb;
      ql[ds][j] = (short)f2bf(v - bf2f(hb));
    }

  // Phase B: stream K fragment tiles; scores via 3-term hi/lo MFMA; value dim = 1
  u16* kbuf = (u16*)&bufA[0][0];
  float* u_s = &bufB[0][0];
  const u16* KH = (const u16*)ws;
  const u16* KL = KH + KH_SZU;
  size_t plane = (size_t)((a * B_ + b) * KV_ + kv) * KPLANE;
  const u16* KHg = KH + plane;
  const u16* KLg = KL + plane;
  const float* Ug = ws + U_OFF + ((size_t)(a * B_ + b) * H_ + h) * S_;
  float num[4] = {}, den[4] = {};
  for (int k0 = 0; k0 < S_; k0 += 64) {
    __syncthreads();
    // stage 16 frags (4 st x 2 ds x 2 planes) = 16 KB, frag-ordered: f = st*4+ds*2+p
#pragma unroll
    for (int i = 0; i < 4; ++i) {
      int c = tid + TB * i;               // 0..1023 chunks of 16 B
      int f = c >> 6, ln = c & 63;
      int st = f >> 2, ds = (f >> 1) & 1, p = f & 1;
      const u16* src = (p ? KLg : KHg) +
                       ((size_t)(((k0 >> 4) + st) * 2 + ds)) * 512 + (size_t)ln * 8;
      *reinterpret_cast<uint4*>(kbuf + (size_t)c * 8) = *reinterpret_cast<const uint4*>(src);
    }
    if (tid < 16)
      *reinterpret_cast<float4*>(u_s + tid * 4) =
          *reinterpret_cast<const float4*>(Ug + k0 + tid * 4);
    __syncthreads();
    const sh8* kb = (const sh8*)kbuf;
#pragma unroll
    for (int st = 0; st < 4; ++st) {
      sh8 bh0 = kb[(st * 4 + 0) * 64 + lane];
      sh8 bl0 = kb[(st * 4 + 1) * 64 + lane];
      sh8 bh1 = kb[(st * 4 + 2) * 64 + lane];
      sh8 bl1 = kb[(st * 4 + 3) * 64 + lane];
      fl4 C = {0.f, 0.f, 0.f, 0.f};
      C = __builtin_amdgcn_mfma_f32_16x16x32_bf16(ql[0], bh0, C, 0, 0, 0);
      C = __builtin_amdgcn_mfma_f32_16x16x32_bf16(ql[1], bh1, C, 0, 0, 0);
      C = __builtin_amdgcn_mfma_f32_16x16x32_bf16(qh[0], bl0, C, 0, 0, 0);
      C = __builtin_amdgcn_mfma_f32_16x16x32_bf16(qh[1], bl1, C, 0, 0, 0);
      C = __builtin_amdgcn_mfma_f32_16x16x32_bf16(qh[0], bh0, C, 0, 0, 0);
      C = __builtin_amdgcn_mfma_f32_16x16x32_bf16(qh[1], bh1, C, 0, 0, 0);
      // C/D layout: col(lane&15) = key within st-tile, row = quad*4 + r = q within 16
      float uval = u_s[st * 16 + col];
#pragma unroll
      for (int r = 0; r < 4; ++r) {
        float e = __expf(C[r] * 0.125f);
        den[r] += e;
        num[r] += e * uval;
      }
    }
  }
  // reduce across the 16 key-lanes (same quad group)
#pragma unroll
  for (int off = 1; off < 16; off <<= 1)
#pragma unroll
    for (int r = 0; r < 4; ++r) {
      den[r] += __shfl_xor(den[r], off);
      num[r] += __shfl_xor(num[r], off);
    }
  if (col == 0) {
#pragma unroll
    for (int r = 0; r < 4; ++r) {
      int q = q0 + w * 16 + quad * 4 + r;
      ws[SH_OFF + ((size_t)(a * B_ + b) * S_ + q) * H_ + h] = num[r] / den[r];
    }
  }
}

// ---- sum heads; w = sigmoid(s2); fp64 reduce sigmoid(s1) per batch ----
__global__ __launch_bounds__(TB) void post_kernel(float* __restrict__ ws) {
  int g = blockIdx.x * TB + threadIdx.x;
  int b = g >> 11, q = g & (S_ - 1);
  const float* sh = ws + SH_OFF;
  float s1 = 0.f, s2 = 0.f;
#pragma unroll
  for (int h = 0; h < H_; ++h) {
    s1 += sh[((size_t)b * S_ + q) * H_ + h];
    s2 += sh[((size_t)(B_ + b) * S_ + q) * H_ + h];
  }
  ws[W_OFF + g] = 1.f / (1.f + expf(-s2));
  double sig = 1.0 / (1.0 + exp(-(double)s1));
#pragma unroll
  for (int off = 1; off < 64; off <<= 1) sig += __shfl_xor(sig, off);
  __shared__ double red[4];
  int tid = threadIdx.x;
  if ((tid & 63) == 0) red[tid >> 6] = sig;
  __syncthreads();
  if (tid == 0)
    atomicAdd(reinterpret_cast<double*>(ws + SUM_OFF) + b,
              red[0] + red[1] + red[2] + red[3]);
}

__global__ void sizes_kernel(const float* __restrict__ scale_p, float* __restrict__ ws,
                             float* __restrict__ out_sizes) {
  int b = threadIdx.x;
  if (b < B_) {
    double m = reinterpret_cast<const double*>(ws + SUM_OFF)[b] / (double)S_;
    double v = m * (double)(*scale_p) * (double)(8192 - 32) + 32.0;
    int sz = (int)v;  // truncation, matches .astype(int32)
    reinterpret_cast<int*>(ws + SIZES_OFF)[b] = sz;
    out_sizes[b] = (float)sz;
  }
}

// ---- weighted segment pooling with exact np.linspace boundaries ----
__global__ __launch_bounds__(TB) void pool_kernel(
    const float* __restrict__ x, const float* __restrict__ ws,
    float* __restrict__ out, int max_len) {
  int p = blockIdx.x, b = blockIdx.y;
  int sz = reinterpret_cast<const int*>(ws + SIZES_OFF)[b];
  int s = p - (max_len - sz);
  int tid = threadIdx.x;
  size_t obase = ((size_t)b * max_len + p) * HID_;
  size_t maskbase = (size_t)B_ * max_len * HID_;
  if (s < 0) {
    *reinterpret_cast<float4*>(out + obase + tid * 4) = make_float4(0.f, 0.f, 0.f, 0.f);
    if (tid == 0) out[maskbase + (size_t)b * max_len + p] = 0.f;
    return;
  }
  double step = (double)S_ / (double)sz;  // np.linspace step in fp64
  int t0 = (int)floor((double)s * step);
  int t1 = (s + 1 == sz) ? S_ : (int)floor((double)(s + 1) * step);
  const float* wv = ws + W_OFF + (size_t)b * S_;
  const float* xb = x + (size_t)b * S_ * HID_;
  float den = 0.f, acc0 = 0.f, acc1 = 0.f, acc2 = 0.f, acc3 = 0.f;
  for (int t = t0; t < t1; ++t) {
    float wt = wv[t];
    den += wt;
    float4 xv = *reinterpret_cast<const float4*>(xb + (size_t)t * HID_ + tid * 4);
    acc0 += xv.x * wt; acc1 += xv.y * wt; acc2 += xv.z * wt; acc3 += xv.w * wt;
  }
  float d = den + 1e-8f;
  *reinterpret_cast<float4*>(out + obase + tid * 4) =
      make_float4(acc0 / d, acc1 / d, acc2 / d, acc3 / d);
  if (tid == 0) out[maskbase + (size_t)b * max_len + p] = 1.f;
}

extern "C" void kernel_launch(void* const* d_in, const int* in_sizes, int n_in,
                              void* d_out, int out_size, void* d_ws, size_t ws_size,
                              hipStream_t stream) {
  const float* x    = (const float*)d_in[0];
  const float* Wq1  = (const float*)d_in[1];
  const float* Wk1  = (const float*)d_in[2];
  const float* Wv1  = (const float*)d_in[3];
  const float* Wo1  = (const float*)d_in[4];
  const float* Wq2  = (const float*)d_in[5];
  const float* Wk2  = (const float*)d_in[6];
  const float* Wv2  = (const float*)d_in[7];
  const float* Wo2  = (const float*)d_in[8];
  const float* scale = (const float*)d_in[9];
  float* ws  = (float*)d_ws;
  float* out = (float*)d_out;

  // out layout: pooled[B][max_len][HID], mask[B][max_len], sizes[B]
  int max_len = (out_size - B_) / (B_ * (HID_ + 1));

  hipMemsetAsync((void*)(ws + SUM_OFF), 0, 4 * sizeof(double), stream);
  wvo_kernel<<<32, TB, 0, stream>>>(Wv1, Wo1, Wv2, Wo2, ws);
  k_gemm_kernel<<<dim3(S_ / 64, KV_, 8), TB, 0, stream>>>(x, Wk1, Wk2, ws);
  u_gemm_kernel<<<dim3(S_ / 64, B_), TB, 0, stream>>>(x, ws);
  attn_kernel<<<dim3(S_ / 64, 32, B_), TB, 0, stream>>>(x, Wq1, Wq2, ws);
  post_kernel<<<(B_ * S_) / TB, TB, 0, stream>>>(ws);
  float* out_sizes = out + (size_t)B_ * max_len * HID_ + (size_t)B_ * max_len;
  sizes_kernel<<<1, 64, 0, stream>>>(scale, ws, out_sizes);
  pool_kernel<<<dim3(max_len, B_), TB, 0, stream>>>(x, ws, out, max_len);
}

// Round 3
// 598.756 us; speedup vs baseline: 2.8804x; 1.8023x over previous
//
#include <hip/hip_runtime.h>
#include <math.h>

#define TB 256

constexpr int B_ = 4, S_ = 2048, HID_ = 1024, H_ = 16, KV_ = 4, D_ = 64;

typedef short sh8 __attribute__((ext_vector_type(8)));   // 8 bf16 in 4 VGPRs
typedef float fl4 __attribute__((ext_vector_type(4)));
typedef unsigned short u16;
typedef unsigned int u32;

__device__ __forceinline__ u16 f2bf(float f) {  // RNE float->bf16 bits
  u32 u = __float_as_uint(f);
  u += 0x7fff + ((u >> 16) & 1);
  return (u16)(u >> 16);
}
__device__ __forceinline__ float bf2f(u16 h) { return __uint_as_float(((u32)h) << 16); }

// ---- workspace layout ----
// u16-unit offsets from ws base. Fragment layouts (verified by R2's K path):
//   A-frag (16x16x32): lane=quad*16+col holds A[m=col][k=quad*8+j], 16B/lane.
//   B-frag:            lane=quad*16+col holds B[k=quad*8+j][n=col], 16B/lane.
constexpr size_t XSZ   = (size_t)B_ * S_ * HID_;          // 8,388,608 per plane
constexpr size_t XH_O  = 0;
constexpr size_t XL_O  = XSZ;
constexpr size_t WQH_O = 2 * XSZ;                          // 16,777,216
constexpr size_t WQSZ  = (size_t)2 * HID_ * (H_ * D_);     // 2,097,152
constexpr size_t WQL_O = WQH_O + WQSZ;
constexpr size_t WKH_O = WQH_O + 2 * WQSZ;                 // 20,971,520
constexpr size_t WKSZ  = (size_t)2 * HID_ * (KV_ * D_);    // 524,288
constexpr size_t WKL_O = WKH_O + WKSZ;
constexpr size_t KH_O  = WKH_O + 2 * WKSZ;                 // 22,020,096
constexpr size_t KSZ   = (size_t)2 * B_ * KV_ * S_ * D_;   // 4,194,304
constexpr size_t KL_O  = KH_O + KSZ;
constexpr size_t KPLANE = (size_t)S_ * D_;                 // 131,072 per (a,b,kv)
// float-unit offsets
constexpr size_t FBASE   = (KH_O + 2 * KSZ) / 2;           // 15,204,352
constexpr size_t U_OFF   = FBASE;                          // U[a][b][h][k]
constexpr size_t U_SZ    = (size_t)2 * B_ * H_ * S_;       // 262,144
constexpr size_t WVO_OFF = U_OFF + U_SZ;                   // wvoT[c][n]
constexpr size_t WVO_SZ  = (size_t)HID_ * 32;              // 32,768
constexpr size_t SH_OFF  = WVO_OFF + WVO_SZ;               // Sh[a*4+b][q][h]
constexpr size_t SH_SZ   = (size_t)2 * B_ * S_ * H_;       // 262,144
constexpr size_t W_OFF   = SH_OFF + SH_SZ;                 // w[b][q]
constexpr size_t W_SZ    = (size_t)B_ * S_;                // 8,192
constexpr size_t SUM_OFF = W_OFF + W_SZ;                   // 4 doubles
constexpr size_t SIZES_OFF = SUM_OFF + 8;                  // 4 ints

// ---- x -> hi/lo bf16 A-fragment planes ----
__global__ __launch_bounds__(TB) void conv_x_kernel(
    const float* __restrict__ x, float* __restrict__ ws) {
  u16* XH = (u16*)ws;
  u16* XL = XH + XSZ;
  int bt = blockIdx.x;  // b*128 + t16
  int tid = threadIdx.x, w = tid >> 6, lane = tid & 63, quad = lane >> 4, col = lane & 15;
  int b = bt >> 7, t16 = bt & 127;
  const float* row = x + ((size_t)b * S_ + t16 * 16 + col) * HID_;
#pragma unroll
  for (int i = 0; i < 8; ++i) {
    int cs = w + i * 4;
    const float* src = row + cs * 32 + quad * 8;
    float4 v0 = *reinterpret_cast<const float4*>(src);
    float4 v1 = *reinterpret_cast<const float4*>(src + 4);
    float vv[8] = {v0.x, v0.y, v0.z, v0.w, v1.x, v1.y, v1.z, v1.w};
    sh8 hh, ll;
#pragma unroll
    for (int j = 0; j < 8; ++j) {
      u16 hb = f2bf(vv[j]);
      hh[j] = (short)hb;
      ll[j] = (short)f2bf(vv[j] - bf2f(hb));
    }
    size_t fb = ((size_t)bt * 32 + cs) * 512 + (size_t)lane * 8;
    *reinterpret_cast<sh8*>(XH + fb) = hh;
    *reinterpret_cast<sh8*>(XL + fb) = ll;
  }
}

// ---- W (HID x ncols, 2 models) -> hi/lo bf16 B-fragment planes ----
__global__ __launch_bounds__(TB) void conv_w_kernel(
    const float* __restrict__ W1, const float* __restrict__ W2,
    u16* __restrict__ OH, u16* __restrict__ OL, int ncols) {
  __shared__ float wt[32][257];
  int ngrp = ncols >> 8;                 // 256-col groups
  int blk = blockIdx.x;                  // a*(32*ngrp) + cs*ngrp + ng
  int a = blk / (32 * ngrp);
  int rem = blk - a * 32 * ngrp;
  int cs = rem / ngrp, ng = rem - cs * ngrp;
  const float* W = a ? W2 : W1;
  int tid = threadIdx.x;
#pragma unroll
  for (int i = 0; i < 8; ++i) {
    int e = tid + i * 256;               // float4 index in 32x256 tile
    int r = e >> 6, c4 = (e & 63) * 4;
    float4 v = *reinterpret_cast<const float4*>(
        W + ((size_t)(cs * 32 + r)) * ncols + ng * 256 + c4);
    wt[r][c4] = v.x; wt[r][c4 + 1] = v.y; wt[r][c4 + 2] = v.z; wt[r][c4 + 3] = v.w;
  }
  __syncthreads();
  int w = tid >> 6, lane = tid & 63, quad = lane >> 4, col = lane & 15;
  int NF = ncols >> 4;
#pragma unroll
  for (int f = 0; f < 4; ++f) {
    int n16 = w * 4 + f;                 // within this 256-col group
    sh8 hh, ll;
#pragma unroll
    for (int j = 0; j < 8; ++j) {
      float v = wt[quad * 8 + j][n16 * 16 + col];
      u16 hb = f2bf(v);
      hh[j] = (short)hb;
      ll[j] = (short)f2bf(v - bf2f(hb));
    }
    size_t fb = (((size_t)a * 32 + cs) * NF + ng * 16 + n16) * 512 + (size_t)lane * 8;
    *reinterpret_cast<sh8*>(OH + fb) = hh;
    *reinterpret_cast<sh8*>(OL + fb) = ll;
  }
}

// ---- fold Wv @ Wo per head: wvoT[c][a*16+h] ----
__global__ __launch_bounds__(TB) void wvo_kernel(
    const float* __restrict__ Wv1, const float* __restrict__ Wo1,
    const float* __restrict__ Wv2, const float* __restrict__ Wo2,
    float* __restrict__ ws) {
  int n = blockIdx.x;  // a*16+h
  int a = n >> 4, h = n & 15, kv = h >> 2;
  const float* Wv = a ? Wv2 : Wv1;
  const float* Wo = a ? Wo2 : Wo1;
  for (int c = threadIdx.x; c < HID_; c += TB) {
    const float* vr = Wv + (size_t)c * (KV_ * D_) + kv * D_;
    const float* wo = Wo + h * D_;
    float acc = 0.f;
#pragma unroll 16
    for (int d = 0; d < D_; ++d) acc += vr[d] * wo[d];
    ws[WVO_OFF + (size_t)c * 32 + n] = acc;
  }
}

// ---- K projection via hi/lo MFMA -> hi/lo bf16 B-fragment planes for phase B ----
__global__ __launch_bounds__(TB) void k_gemm_kernel(float* __restrict__ ws) {
  __shared__ __align__(16) float xs[64][68];   // [key][d]
  int k0 = blockIdx.x * 64;
  int kv = blockIdx.y;
  int ab = blockIdx.z, a = ab >> 2, b = ab & 3;
  int tid = threadIdx.x, w = tid >> 6, lane = tid & 63, quad = lane >> 4, col = lane & 15;
  const u16* XH = (const u16*)ws;
  const u16* XL = XH + XSZ;
  const u16* WKH = XH + WKH_O;
  const u16* WKL = XH + WKL_O;
  int tq = (w & 1) * 2, nq = (w >> 1) * 2;
  fl4 C[2][2] = {};
#pragma unroll 2
  for (int cs = 0; cs < 32; ++cs) {
    sh8 ah[2], al[2], bh[2], bl[2];
#pragma unroll
    for (int ti = 0; ti < 2; ++ti) {
      size_t fb = (((size_t)b * 128 + (k0 >> 4) + tq + ti) * 32 + cs) * 512 + (size_t)lane * 8;
      ah[ti] = *reinterpret_cast<const sh8*>(XH + fb);
      al[ti] = *reinterpret_cast<const sh8*>(XL + fb);
    }
#pragma unroll
    for (int ni = 0; ni < 2; ++ni) {
      size_t fb = (((size_t)a * 32 + cs) * 16 + kv * 4 + nq + ni) * 512 + (size_t)lane * 8;
      bh[ni] = *reinterpret_cast<const sh8*>(WKH + fb);
      bl[ni] = *reinterpret_cast<const sh8*>(WKL + fb);
    }
#pragma unroll
    for (int ti = 0; ti < 2; ++ti)
#pragma unroll
      for (int ni = 0; ni < 2; ++ni) {
        C[ti][ni] = __builtin_amdgcn_mfma_f32_16x16x32_bf16(ah[ti], bh[ni], C[ti][ni], 0, 0, 0);
        C[ti][ni] = __builtin_amdgcn_mfma_f32_16x16x32_bf16(al[ti], bh[ni], C[ti][ni], 0, 0, 0);
        C[ti][ni] = __builtin_amdgcn_mfma_f32_16x16x32_bf16(ah[ti], bl[ni], C[ti][ni], 0, 0, 0);
      }
  }
#pragma unroll
  for (int ti = 0; ti < 2; ++ti)
#pragma unroll
    for (int ni = 0; ni < 2; ++ni)
#pragma unroll
      for (int r = 0; r < 4; ++r)
        xs[(tq + ti) * 16 + quad * 4 + r][(nq + ni) * 16 + col] = C[ti][ni][r];
  __syncthreads();
  // emit hi/lo bf16 B-fragments (same as R2)
  u16* KH = (u16*)ws + KH_O;
  u16* KL = (u16*)ws + KL_O;
  size_t plane = (size_t)((a * B_ + b) * KV_ + kv) * KPLANE;
#pragma unroll
  for (int t = 0; t < 2; ++t) {
    int f = w + t * 4;                   // 0..7
    int k16 = f & 3, ds = f >> 2;
    const float* row = &xs[k16 * 16 + col][ds * 32 + quad * 8];
    sh8 hh, ll;
#pragma unroll
    for (int j = 0; j < 8; ++j) {
      float v = row[j];
      u16 hb = f2bf(v);
      hh[j] = (short)hb;
      ll[j] = (short)f2bf(v - bf2f(hb));
    }
    size_t fb = plane + ((size_t)(((k0 >> 4) + k16) * 2 + ds)) * 512 + (size_t)lane * 8;
    *reinterpret_cast<sh8*>(KH + fb) = hh;
    *reinterpret_cast<sh8*>(KL + fb) = ll;
  }
}

// ---- U = x @ wvoT : U[a][b][h][k] (fp32 vector; small) ----
__global__ __launch_bounds__(TB) void u_gemm_kernel(
    const float* __restrict__ x, float* __restrict__ ws) {
  __shared__ float xs[64][68];   // [k][c]
  __shared__ float uw[64][36];   // [c][n]
  int k0 = blockIdx.x * 64, b = blockIdx.y;
  int tid = threadIdx.x;
  int tk = tid >> 2, ng = tid & 3;
  int lr = tid >> 4, lc4 = (tid & 15) * 4;
  float acc[8] = {};
  for (int c0 = 0; c0 < HID_; c0 += 64) {
    __syncthreads();
#pragma unroll
    for (int p = 0; p < 4; ++p) {
      int r = lr + p * 16;
      *reinterpret_cast<float4*>(&xs[r][lc4]) =
          *reinterpret_cast<const float4*>(x + ((size_t)(b * S_ + k0 + r) * HID_ + c0 + lc4));
    }
    {
      int cc = tid >> 3, n4 = (tid & 7) * 4;
      *reinterpret_cast<float4*>(&uw[cc][n4]) =
          *reinterpret_cast<const float4*>(ws + WVO_OFF + (size_t)(c0 + cc) * 32 + n4);
      *reinterpret_cast<float4*>(&uw[cc + 32][n4]) =
          *reinterpret_cast<const float4*>(ws + WVO_OFF + (size_t)(c0 + cc + 32) * 32 + n4);
    }
    __syncthreads();
#pragma unroll 8
    for (int cc = 0; cc < 64; ++cc) {
      float xv = xs[tk][cc];
      float4 a0 = *reinterpret_cast<const float4*>(&uw[cc][ng * 8]);
      float4 a1 = *reinterpret_cast<const float4*>(&uw[cc][ng * 8 + 4]);
      acc[0] += xv * a0.x; acc[1] += xv * a0.y; acc[2] += xv * a0.z; acc[3] += xv * a0.w;
      acc[4] += xv * a1.x; acc[5] += xv * a1.y; acc[6] += xv * a1.z; acc[7] += xv * a1.w;
    }
  }
#pragma unroll
  for (int j = 0; j < 8; ++j) {
    int n = ng * 8 + j, a = n >> 4, h = n & 15;
    ws[U_OFF + ((size_t)(a * B_ + b) * H_ + h) * S_ + k0 + tk] = acc[j];
  }
}

// ---- fused: MFMA Q-proj (phase A) + hi/lo bf16 MFMA QK^T + scalar-value softmax ----
__global__ __launch_bounds__(TB) void attn_kernel(float* __restrict__ ws) {
  __shared__ __align__(16) float Qt[64][68];    // [d][q] fp32
  __shared__ __align__(16) u16 kbuf[16 * 512];  // 16 frags x 1 KB
  __shared__ float u_s[64];
  int q0 = blockIdx.x * 64;
  int ah = blockIdx.y, a = ah >> 4, h = ah & 15, kv = h >> 2;
  int b = blockIdx.z;
  int tid = threadIdx.x, w = tid >> 6, lane = tid & 63, quad = lane >> 4, col = lane & 15;
  const u16* XH = (const u16*)ws;
  const u16* XL = XH + XSZ;
  const u16* WQH = XH + WQH_O;
  const u16* WQL = XH + WQL_O;

  // Phase A: Qt = x_tile @ Wq[:, h*64 .. h*64+64)  via hi/lo MFMA, barrier-free
  {
    int tq = (w & 1) * 2, nq = (w >> 1) * 2;
    fl4 C[2][2] = {};
#pragma unroll 2
    for (int cs = 0; cs < 32; ++cs) {
      sh8 ah_[2], al_[2], bh_[2], bl_[2];
#pragma unroll
      for (int ti = 0; ti < 2; ++ti) {
        size_t fb = (((size_t)b * 128 + (q0 >> 4) + tq + ti) * 32 + cs) * 512 + (size_t)lane * 8;
        ah_[ti] = *reinterpret_cast<const sh8*>(XH + fb);
        al_[ti] = *reinterpret_cast<const sh8*>(XL + fb);
      }
#pragma unroll
      for (int ni = 0; ni < 2; ++ni) {
        size_t fb = (((size_t)a * 32 + cs) * 64 + h * 4 + nq + ni) * 512 + (size_t)lane * 8;
        bh_[ni] = *reinterpret_cast<const sh8*>(WQH + fb);
        bl_[ni] = *reinterpret_cast<const sh8*>(WQL + fb);
      }
#pragma unroll
      for (int ti = 0; ti < 2; ++ti)
#pragma unroll
        for (int ni = 0; ni < 2; ++ni) {
          C[ti][ni] = __builtin_amdgcn_mfma_f32_16x16x32_bf16(ah_[ti], bh_[ni], C[ti][ni], 0, 0, 0);
          C[ti][ni] = __builtin_amdgcn_mfma_f32_16x16x32_bf16(al_[ti], bh_[ni], C[ti][ni], 0, 0, 0);
          C[ti][ni] = __builtin_amdgcn_mfma_f32_16x16x32_bf16(ah_[ti], bl_[ni], C[ti][ni], 0, 0, 0);
        }
    }
#pragma unroll
    for (int ti = 0; ti < 2; ++ti)
#pragma unroll
      for (int ni = 0; ni < 2; ++ni)
#pragma unroll
        for (int r = 0; r < 4; ++r)
          Qt[(nq + ni) * 16 + col][(tq + ti) * 16 + quad * 4 + r] = C[ti][ni][r];
  }
  __syncthreads();

  // Build hi/lo Q A-fragments (lane holds Q[q=w*16+col][d=ds*32+quad*8+j])
  sh8 qh[2], ql[2];
#pragma unroll
  for (int ds = 0; ds < 2; ++ds)
#pragma unroll
    for (int j = 0; j < 8; ++j) {
      float v = Qt[ds * 32 + quad * 8 + j][w * 16 + col];
      u16 hb = f2bf(v);
      qh[ds][j] = (short)hb;
      ql[ds][j] = (short)f2bf(v - bf2f(hb));
    }

  // Phase B: stream K fragment tiles; scores via 3-term hi/lo MFMA; value dim = 1
  const u16* KHg = (const u16*)ws + KH_O + (size_t)((a * B_ + b) * KV_ + kv) * KPLANE;
  const u16* KLg = (const u16*)ws + KL_O + (size_t)((a * B_ + b) * KV_ + kv) * KPLANE;
  const float* Ug = ws + U_OFF + ((size_t)(a * B_ + b) * H_ + h) * S_;
  float num[4] = {}, den[4] = {};
  for (int k0 = 0; k0 < S_; k0 += 64) {
    __syncthreads();
#pragma unroll
    for (int i = 0; i < 4; ++i) {
      int c = tid + TB * i;               // 0..1023 chunks of 16 B
      int f = c >> 6, ln = c & 63;
      int st = f >> 2, ds = (f >> 1) & 1, p = f & 1;
      const u16* src = (p ? KLg : KHg) +
                       ((size_t)(((k0 >> 4) + st) * 2 + ds)) * 512 + (size_t)ln * 8;
      *reinterpret_cast<uint4*>(kbuf + (size_t)c * 8) = *reinterpret_cast<const uint4*>(src);
    }
    if (tid < 16)
      *reinterpret_cast<float4*>(u_s + tid * 4) =
          *reinterpret_cast<const float4*>(Ug + k0 + tid * 4);
    __syncthreads();
    const sh8* kb = (const sh8*)kbuf;
#pragma unroll
    for (int st = 0; st < 4; ++st) {
      sh8 bh0 = kb[(st * 4 + 0) * 64 + lane];
      sh8 bl0 = kb[(st * 4 + 1) * 64 + lane];
      sh8 bh1 = kb[(st * 4 + 2) * 64 + lane];
      sh8 bl1 = kb[(st * 4 + 3) * 64 + lane];
      fl4 C = {0.f, 0.f, 0.f, 0.f};
      C = __builtin_amdgcn_mfma_f32_16x16x32_bf16(ql[0], bh0, C, 0, 0, 0);
      C = __builtin_amdgcn_mfma_f32_16x16x32_bf16(ql[1], bh1, C, 0, 0, 0);
      C = __builtin_amdgcn_mfma_f32_16x16x32_bf16(qh[0], bl0, C, 0, 0, 0);
      C = __builtin_amdgcn_mfma_f32_16x16x32_bf16(qh[1], bl1, C, 0, 0, 0);
      C = __builtin_amdgcn_mfma_f32_16x16x32_bf16(qh[0], bh0, C, 0, 0, 0);
      C = __builtin_amdgcn_mfma_f32_16x16x32_bf16(qh[1], bh1, C, 0, 0, 0);
      float uval = u_s[st * 16 + col];
#pragma unroll
      for (int r = 0; r < 4; ++r) {
        float e = __expf(C[r] * 0.125f);
        den[r] += e;
        num[r] += e * uval;
      }
    }
  }
#pragma unroll
  for (int off = 1; off < 16; off <<= 1)
#pragma unroll
    for (int r = 0; r < 4; ++r) {
      den[r] += __shfl_xor(den[r], off);
      num[r] += __shfl_xor(num[r], off);
    }
  if (col == 0) {
#pragma unroll
    for (int r = 0; r < 4; ++r) {
      int q = q0 + w * 16 + quad * 4 + r;
      ws[SH_OFF + ((size_t)(a * B_ + b) * S_ + q) * H_ + h] = num[r] / den[r];
    }
  }
}

// ---- sum heads; w = sigmoid(s2); fp64 reduce sigmoid(s1) per batch ----
__global__ __launch_bounds__(TB) void post_kernel(float* __restrict__ ws) {
  int g = blockIdx.x * TB + threadIdx.x;
  int b = g >> 11, q = g & (S_ - 1);
  const float* sh = ws + SH_OFF;
  float s1 = 0.f, s2 = 0.f;
#pragma unroll
  for (int h = 0; h < H_; ++h) {
    s1 += sh[((size_t)b * S_ + q) * H_ + h];
    s2 += sh[((size_t)(B_ + b) * S_ + q) * H_ + h];
  }
  ws[W_OFF + g] = 1.f / (1.f + expf(-s2));
  double sig = 1.0 / (1.0 + exp(-(double)s1));
#pragma unroll
  for (int off = 1; off < 64; off <<= 1) sig += __shfl_xor(sig, off);
  __shared__ double red[4];
  int tid = threadIdx.x;
  if ((tid & 63) == 0) red[tid >> 6] = sig;
  __syncthreads();
  if (tid == 0)
    atomicAdd(reinterpret_cast<double*>(ws + SUM_OFF) + b,
              red[0] + red[1] + red[2] + red[3]);
}

__global__ void sizes_kernel(const float* __restrict__ scale_p, float* __restrict__ ws,
                             float* __restrict__ out_sizes) {
  int b = threadIdx.x;
  if (b < B_) {
    double m = reinterpret_cast<const double*>(ws + SUM_OFF)[b] / (double)S_;
    double v = m * (double)(*scale_p) * (double)(8192 - 32) + 32.0;
    int sz = (int)v;  // truncation, matches .astype(int32)
    reinterpret_cast<int*>(ws + SIZES_OFF)[b] = sz;
    out_sizes[b] = (float)sz;
  }
}

// ---- weighted segment pooling with exact np.linspace boundaries ----
__global__ __launch_bounds__(TB) void pool_kernel(
    const float* __restrict__ x, const float* __restrict__ ws,
    float* __restrict__ out, int max_len) {
  int p = blockIdx.x, b = blockIdx.y;
  int sz = reinterpret_cast<const int*>(ws + SIZES_OFF)[b];
  int s = p - (max_len - sz);
  int tid = threadIdx.x;
  size_t obase = ((size_t)b * max_len + p) * HID_;
  size_t maskbase = (size_t)B_ * max_len * HID_;
  if (s < 0) {
    *reinterpret_cast<float4*>(out + obase + tid * 4) = make_float4(0.f, 0.f, 0.f, 0.f);
    if (tid == 0) out[maskbase + (size_t)b * max_len + p] = 0.f;
    return;
  }
  double step = (double)S_ / (double)sz;  // np.linspace step in fp64
  int t0 = (int)floor((double)s * step);
  int t1 = (s + 1 == sz) ? S_ : (int)floor((double)(s + 1) * step);
  const float* wv = ws + W_OFF + (size_t)b * S_;
  const float* xb = x + (size_t)b * S_ * HID_;
  float den = 0.f, acc0 = 0.f, acc1 = 0.f, acc2 = 0.f, acc3 = 0.f;
  for (int t = t0; t < t1; ++t) {
    float wt = wv[t];
    den += wt;
    float4 xv = *reinterpret_cast<const float4*>(xb + (size_t)t * HID_ + tid * 4);
    acc0 += xv.x * wt; acc1 += xv.y * wt; acc2 += xv.z * wt; acc3 += xv.w * wt;
  }
  float d = den + 1e-8f;
  *reinterpret_cast<float4*>(out + obase + tid * 4) =
      make_float4(acc0 / d, acc1 / d, acc2 / d, acc3 / d);
  if (tid == 0) out[maskbase + (size_t)b * max_len + p] = 1.f;
}

extern "C" void kernel_launch(void* const* d_in, const int* in_sizes, int n_in,
                              void* d_out, int out_size, void* d_ws, size_t ws_size,
                              hipStream_t stream) {
  const float* x    = (const float*)d_in[0];
  const float* Wq1  = (const float*)d_in[1];
  const float* Wk1  = (const float*)d_in[2];
  const float* Wv1  = (const float*)d_in[3];
  const float* Wo1  = (const float*)d_in[4];
  const float* Wq2  = (const float*)d_in[5];
  const float* Wk2  = (const float*)d_in[6];
  const float* Wv2  = (const float*)d_in[7];
  const float* Wo2  = (const float*)d_in[8];
  const float* scale = (const float*)d_in[9];
  float* ws  = (float*)d_ws;
  u16* wsu   = (u16*)d_ws;
  float* out = (float*)d_out;

  // out layout: pooled[B][max_len][HID], mask[B][max_len], sizes[B]
  int max_len = (out_size - B_) / (B_ * (HID_ + 1));

  hipMemsetAsync((void*)(ws + SUM_OFF), 0, 4 * sizeof(double), stream);
  conv_x_kernel<<<B_ * (S_ / 16), TB, 0, stream>>>(x, ws);
  conv_w_kernel<<<2 * 32 * 4, TB, 0, stream>>>(Wq1, Wq2, wsu + WQH_O, wsu + WQL_O, H_ * D_);
  conv_w_kernel<<<2 * 32 * 1, TB, 0, stream>>>(Wk1, Wk2, wsu + WKH_O, wsu + WKL_O, KV_ * D_);
  wvo_kernel<<<32, TB, 0, stream>>>(Wv1, Wo1, Wv2, Wo2, ws);
  k_gemm_kernel<<<dim3(S_ / 64, KV_, 8), TB, 0, stream>>>(ws);
  u_gemm_kernel<<<dim3(S_ / 64, B_), TB, 0, stream>>>(x, ws);
  attn_kernel<<<dim3(S_ / 64, 32, B_), TB, 0, stream>>>(ws);
  post_kernel<<<(B_ * S_) / TB, TB, 0, stream>>>(ws);
  float* out_sizes = out + (size_t)B_ * max_len * HID_ + (size_t)B_ * max_len;
  sizes_kernel<<<1, 64, 0, stream>>>(scale, ws, out_sizes);
  pool_kernel<<<dim3(max_len, B_), TB, 0, stream>>>(x, ws, out, max_len);
}